// Round 3
// baseline (762.641 us; speedup 1.0000x reference)
//
#include <hip/hip_runtime.h>

typedef __bf16 bf16_t;
typedef __attribute__((ext_vector_type(8))) __bf16 bf16x8;
typedef __attribute__((ext_vector_type(4))) float f32x4;

#define M_DIM 8192   // BSZ*SEQ
#define N_DIM 4096   // OUT_DIM
#define K_DIM 4096   // IN_DIM
#define R_DIM 64     // total rank

// ---------------- kernel 1: x fp32 -> bf16 ----------------
__global__ __launch_bounds__(256) void cvt_x(const float* __restrict__ in,
                                             bf16_t* __restrict__ out) {
    size_t i = ((size_t)blockIdx.x * 256 + threadIdx.x) * 8;
    float4 a = *(const float4*)(in + i);
    float4 b = *(const float4*)(in + i + 4);
    bf16x8 v;
    v[0] = (bf16_t)a.x; v[1] = (bf16_t)a.y; v[2] = (bf16_t)a.z; v[3] = (bf16_t)a.w;
    v[4] = (bf16_t)b.x; v[5] = (bf16_t)b.y; v[6] = (bf16_t)b.z; v[7] = (bf16_t)b.w;
    *(bf16x8*)(out + i) = v;
}

// ------- kernel 2: Weff[o][i] = bf16(W[o][i] + sum_r (2*B[o][r])*A[r][i]) -------
__global__ __launch_bounds__(256) void build_weff(const float* __restrict__ W,
                                                  const float* __restrict__ A,
                                                  const float* __restrict__ Bl,
                                                  bf16_t* __restrict__ out) {
    const int i  = blockIdx.x * 256 + threadIdx.x;
    const int o0 = blockIdx.y * 16;

    float acc[16];
#pragma unroll
    for (int j = 0; j < 16; j++) acc[j] = W[(size_t)(o0 + j) * K_DIM + i];

    for (int rh = 0; rh < R_DIM; rh += 16) {   // NOT unrolled: keeps pressure low
        float av[16];
#pragma unroll
        for (int r = 0; r < 16; r++) av[r] = 2.0f * A[(size_t)(rh + r) * K_DIM + i];
#pragma unroll
        for (int j = 0; j < 16; j++) {
#pragma unroll
            for (int r = 0; r < 16; r++)
                acc[j] += Bl[(o0 + j) * R_DIM + rh + r] * av[r];
        }
    }
#pragma unroll
    for (int j = 0; j < 16; j++) out[(size_t)(o0 + j) * K_DIM + i] = (bf16_t)acc[j];
}

// ---------------- kernel 3: C[M][N] = Xb[M][K] * Weff[N][K]^T ----------------
// Producer-consumer pipelined GEMM: waves 0..3 compute (each owns a 64x64
// quadrant of the 128x128 tile); wave 4 stages K-tiles into a 2-deep LDS ring
// via global_load_lds. NO __syncthreads in the K-loop: only the producer waits
// vmcnt(0); consumers never drain -> removes the ~20% barrier-drain stall of
// the 2-barrier m97 structure.
#define BM 128
#define BN 128
#define BK 64        // 8 chunks of 8 bf16 (16 B) per row
#define KT (K_DIM / BK)

#define GLDS(gp, lp) __builtin_amdgcn_global_load_lds(                       \
    (__attribute__((address_space(1))) void*)(gp),                           \
    (__attribute__((address_space(3))) void*)(lp), 16, 0, 0)

__global__ __launch_bounds__(320) void gemm_pc(const bf16_t* __restrict__ Ax,
                                               const bf16_t* __restrict__ Bw,
                                               float* __restrict__ C) {
    // XOR-swizzled tiles: LDS[r][c] holds global chunk (c ^ (r&7)) of row r.
    __shared__ __attribute__((aligned(16))) bf16_t Ash[2][BM * BK];  // 2x16 KiB
    __shared__ __attribute__((aligned(16))) bf16_t Bsh[2][BN * BK];  // 2x16 KiB
    __shared__ int ready[2];  // tiles written into buffer b (monotonic)
    __shared__ int done[2];   // consumer-wave completions on buffer b (monotonic)

    const int tid  = threadIdx.x;
    const int wave = tid >> 6;
    const int lane = tid & 63;
    const int m0 = blockIdx.y * BM;
    const int n0 = blockIdx.x * BN;

    if (tid == 0) { ready[0] = ready[1] = 0; done[0] = done[1] = 0; }
    __syncthreads();  // the only barrier in this kernel

    if (wave == 4) {
        // ---------------- producer ----------------
        const int srow   = lane >> 3;   // row within 8-row staging group
        const int schunk = lane & 7;    // 16B chunk within row
        for (int t = 0; t < KT; t++) {
            const int b = t & 1, n = t >> 1;
            if (t >= 2) {  // wait until all 4 consumers finished previous use
                while (__hip_atomic_load(&done[b], __ATOMIC_ACQUIRE,
                                         __HIP_MEMORY_SCOPE_WORKGROUP) < 4 * n)
                    __builtin_amdgcn_s_sleep(1);
            }
            const int k0 = t * BK;
#pragma unroll
            for (int i = 0; i < 16; i++) {
                const int rb = i * 8;            // wave-uniform group base row
                const int r  = rb + srow;
                const int ca = schunk ^ (r & 7); // swizzled source chunk
                GLDS(Ax + (size_t)(m0 + r) * K_DIM + k0 + ca * 8, &Ash[b][rb * BK]);
            }
#pragma unroll
            for (int i = 0; i < 16; i++) {
                const int rb = i * 8;
                const int r  = rb + srow;
                const int ca = schunk ^ (r & 7);
                GLDS(Bw + (size_t)(n0 + r) * K_DIM + k0 + ca * 8, &Bsh[b][rb * BK]);
            }
            __builtin_amdgcn_s_waitcnt(0x0f70);  // vmcnt(0): tile resident in LDS
            if (lane == 0)
                __hip_atomic_store(&ready[b], n + 1, __ATOMIC_RELEASE,
                                   __HIP_MEMORY_SCOPE_WORKGROUP);
        }
        return;  // producer exits; no barriers follow
    }

    // ---------------- consumers (waves 0..3) ----------------
    const int m16  = lane & 15;
    const int quad = lane >> 4;
    const int wm   = wave >> 1;   // 2x2 wave grid over the 128x128 tile
    const int wn   = wave & 1;

    f32x4 acc[4][4] = {};

    for (int t = 0; t < KT; t++) {
        const int b = t & 1, n = t >> 1;
        while (__hip_atomic_load(&ready[b], __ATOMIC_ACQUIRE,
                                 __HIP_MEMORY_SCOPE_WORKGROUP) < n + 1)
            __builtin_amdgcn_s_sleep(1);
#pragma unroll
        for (int ks = 0; ks < 2; ks++) {
            bf16x8 afr[4], bfr[4];
#pragma unroll
            for (int tt = 0; tt < 4; tt++) {
                const int mr = wm * 64 + tt * 16 + m16;
                const int nr = wn * 64 + tt * 16 + m16;
                const int ck = ks * 4 + quad;      // logical 16B k-chunk
                afr[tt] = *(const bf16x8*)(&Ash[b][mr * BK + ((ck ^ (mr & 7)) << 3)]);
                bfr[tt] = *(const bf16x8*)(&Bsh[b][nr * BK + ((ck ^ (nr & 7)) << 3)]);
            }
#pragma unroll
            for (int tm = 0; tm < 4; tm++)
#pragma unroll
                for (int tn = 0; tn < 4; tn++)
                    acc[tm][tn] = __builtin_amdgcn_mfma_f32_16x16x32_bf16(
                        afr[tm], bfr[tn], acc[tm][tn], 0, 0, 0);
        }
        // signal consumption; ds ops are pipe-ordered after the frag reads,
        // and the release forces lgkm drain for safety.
        __hip_atomic_fetch_add(&done[b], 1, __ATOMIC_RELEASE,
                               __HIP_MEMORY_SCOPE_WORKGROUP);
    }

    // epilogue: C/D layout col = lane&15, row = quad*4 + reg
#pragma unroll
    for (int tm = 0; tm < 4; tm++) {
#pragma unroll
        for (int i = 0; i < 4; i++) {
            const int gm = m0 + wm * 64 + tm * 16 + quad * 4 + i;
            float* crow = C + (size_t)gm * N_DIM + n0 + wn * 64 + m16;
#pragma unroll
            for (int tn = 0; tn < 4; tn++)
                crow[tn * 16] = acc[tm][tn][i];
        }
    }
}

extern "C" void kernel_launch(void* const* d_in, const int* in_sizes, int n_in,
                              void* d_out, int out_size, void* d_ws, size_t ws_size,
                              hipStream_t stream) {
    const float* x  = (const float*)d_in[0];
    const float* W  = (const float*)d_in[1];
    const float* La = (const float*)d_in[2];
    const float* Lb = (const float*)d_in[3];
    float* out = (float*)d_out;

    // workspace: xb (64 MiB) | Weff (32 MiB)
    bf16_t* xb = (bf16_t*)d_ws;
    bf16_t* wf = (bf16_t*)((char*)d_ws + (size_t)M_DIM * K_DIM * sizeof(bf16_t));

    cvt_x<<<(M_DIM * K_DIM) / (256 * 8), 256, 0, stream>>>(x, xb);
    build_weff<<<dim3(K_DIM / 256, N_DIM / 16), 256, 0, stream>>>(W, La, Lb, wf);
    gemm_pc<<<dim3(N_DIM / BN, M_DIM / BM), 320, 0, stream>>>(xb, wf, out);
}